// Round 1
// baseline (585.879 us; speedup 1.0000x reference)
//
#include <hip/hip_runtime.h>

#define L_ 2048
#define B_ 2
#define E_ 1024
#define H_ 16
#define HD_ 64
#define M_ 4096   // L_*B_
#define K_ 1024   // E_

typedef unsigned short u16;
using short8  = __attribute__((ext_vector_type(8))) short;
using floatx4 = __attribute__((ext_vector_type(4))) float;

__device__ inline u16 f2b(float f) {            // fp32 -> bf16 RNE
  unsigned u = __float_as_uint(f);
  u += 0x7FFF + ((u >> 16) & 1);
  return (u16)(u >> 16);
}

__device__ inline floatx4 mfma16(short8 a, short8 b, floatx4 c) {
  return __builtin_amdgcn_mfma_f32_16x16x32_bf16(a, b, c, 0, 0, 0);
}

// ---------------- fp32 -> bf16 conversion ----------------
__global__ void convk(const float* __restrict__ src, u16* __restrict__ dst, int n4) {
  int i = blockIdx.x * blockDim.x + threadIdx.x;
  if (i < n4) {
    float4 v = ((const float4*)src)[i];
    ushort4 o;
    o.x = f2b(v.x); o.y = f2b(v.y); o.z = f2b(v.z); o.w = f2b(v.w);
    ((ushort4*)dst)[i] = o;
  }
}

// ---------------- bf16 GEMM: C[M,N] = A[M,K] * W[N,K]^T + bias ----------------
// MODE 0: A = x_all (3 slices by blockIdx.z), scatter bf16 into qh/kh (B,H,L,HD) and vhT (B,H,HD,L)
// MODE 1: A = ctx, fp32 output row-major to outp
template <int MODE>
__global__ __launch_bounds__(256) void gemm128(
    const u16* __restrict__ A, const u16* __restrict__ W, const float* __restrict__ bias,
    u16* __restrict__ qh, u16* __restrict__ kh, u16* __restrict__ vhT,
    float* __restrict__ outp)
{
  __shared__ __align__(16) u16 As[128 * 32];
  __shared__ __align__(16) u16 Bs[128 * 32];
  const int p = (MODE == 0) ? blockIdx.z : 0;
  const u16* Ap = A + (size_t)p * M_ * K_;
  const u16* Wp = W + (size_t)p * E_ * K_;
  const float* bp = bias + p * E_;
  const int row0 = blockIdx.y * 128, col0 = blockIdx.x * 128;
  const int t = threadIdx.x, lane = t & 63, wv = t >> 6;
  const int lanem = lane & 15, quad = lane >> 4;
  const int wm = wv >> 1, wn = wv & 1;

  floatx4 acc[4][4];
#pragma unroll
  for (int mi = 0; mi < 4; ++mi)
#pragma unroll
    for (int ni = 0; ni < 4; ++ni) acc[mi][ni] = (floatx4){0.f, 0.f, 0.f, 0.f};

  for (int k0 = 0; k0 < K_; k0 += 32) {
    __syncthreads();
#pragma unroll
    for (int rr = 0; rr < 2; ++rr) {
      int idx = rr * 256 + t;            // 0..511, 8 bf16 each
      int arow = idx >> 2, kc = (idx & 3) * 8;
      *(uint4*)&As[idx * 8] = *(const uint4*)&Ap[(size_t)(row0 + arow) * K_ + k0 + kc];
      *(uint4*)&Bs[idx * 8] = *(const uint4*)&Wp[(size_t)(col0 + arow) * K_ + k0 + kc];
    }
    __syncthreads();
    short8 af[4], bfg[4];
#pragma unroll
    for (int mi = 0; mi < 4; ++mi)
      af[mi] = *(const short8*)&As[(wm * 64 + mi * 16 + lanem) * 32 + quad * 8];
#pragma unroll
    for (int ni = 0; ni < 4; ++ni)
      bfg[ni] = *(const short8*)&Bs[(wn * 64 + ni * 16 + lanem) * 32 + quad * 8];
#pragma unroll
    for (int mi = 0; mi < 4; ++mi)
#pragma unroll
      for (int ni = 0; ni < 4; ++ni)
        acc[mi][ni] = mfma16(af[mi], bfg[ni], acc[mi][ni]);
  }

#pragma unroll
  for (int ni = 0; ni < 4; ++ni) {
    int gc = col0 + wn * 64 + ni * 16 + lanem;
    float bv = bp[gc];
#pragma unroll
    for (int mi = 0; mi < 4; ++mi) {
      int gr0 = row0 + wm * 64 + mi * 16 + quad * 4;
#pragma unroll
      for (int v = 0; v < 4; ++v) {
        float val = acc[mi][ni][v] + bv;
        int r = gr0 + v;
        if (MODE == 1) {
          outp[(size_t)r * E_ + gc] = val;
        } else {
          int l = r >> 1, bb = r & 1, hh = gc >> 6, d = gc & 63;
          u16 x = f2b(val);
          if (p == 0)      qh[(((size_t)bb * H_ + hh) * L_ + l) * HD_ + d] = x;
          else if (p == 1) kh[(((size_t)bb * H_ + hh) * L_ + l) * HD_ + d] = x;
          else             vhT[(((size_t)bb * H_ + hh) * HD_ + d) * L_ + l] = x;
        }
      }
    }
  }
}

// ---------------- flash attention: ctx + per-row (m, 1/l) ----------------
__global__ __launch_bounds__(256) void attn1(
    const u16* __restrict__ qh, const u16* __restrict__ kh, const u16* __restrict__ vhT,
    u16* __restrict__ ctx, float* __restrict__ m_ws, float* __restrict__ li_ws)
{
  __shared__ __align__(16) u16 plds[4][2][512];   // per-wave double-buffered P tile (16x32 bf16)
  const int it = blockIdx.x, h = blockIdx.y, b = blockIdx.z;
  const int t = threadIdx.x, lane = t & 63, wv = t >> 6;
  const int lanem = lane & 15, quad = lane >> 4;
  const int bh = b * H_ + h;
  const int i0 = it * 64 + wv * 16;

  const u16* qb = qh + ((size_t)bh * L_ + i0 + lanem) * HD_;
  short8 qa0 = *(const short8*)(qb + quad * 8);
  short8 qa1 = *(const short8*)(qb + 32 + quad * 8);

  float mi_[4] = {-INFINITY, -INFINITY, -INFINITY, -INFINITY};
  float li_[4] = {0.f, 0.f, 0.f, 0.f};
  floatx4 o[4];
#pragma unroll
  for (int db = 0; db < 4; ++db) o[db] = (floatx4){0.f, 0.f, 0.f, 0.f};

  const int nj = (i0 + 47) >> 5;   // j-tiles of 32 covering rows i0..i0+15
  for (int jt = 0; jt < nj; ++jt) {
    const int j0 = jt * 32;
    u16* pl = plds[wv][jt & 1];
    const u16* kb = kh + ((size_t)bh * L_ + j0) * HD_;
    short8 kb00 = *(const short8*)(kb + lanem * HD_ + quad * 8);
    short8 kb01 = *(const short8*)(kb + lanem * HD_ + 32 + quad * 8);
    short8 kb10 = *(const short8*)(kb + (16 + lanem) * HD_ + quad * 8);
    short8 kb11 = *(const short8*)(kb + (16 + lanem) * HD_ + 32 + quad * 8);
    floatx4 s0 = (floatx4){0.f, 0.f, 0.f, 0.f}, s1 = (floatx4){0.f, 0.f, 0.f, 0.f};
    s0 = mfma16(qa0, kb00, s0); s0 = mfma16(qa1, kb01, s0);
    s1 = mfma16(qa0, kb10, s1); s1 = mfma16(qa1, kb11, s1);

    float alph[4];
#pragma unroll
    for (int r = 0; r < 4; ++r) {
      int irow = i0 + quad * 4 + r;
      float sv0 = (j0 + lanem <= irow) ? s0[r] * 0.125f : -INFINITY;
      float sv1 = (j0 + 16 + lanem <= irow) ? s1[r] * 0.125f : -INFINITY;
      float mx = fmaxf(sv0, sv1);
      mx = fmaxf(mx, __shfl_xor(mx, 1));
      mx = fmaxf(mx, __shfl_xor(mx, 2));
      mx = fmaxf(mx, __shfl_xor(mx, 4));
      mx = fmaxf(mx, __shfl_xor(mx, 8));
      float mnew = fmaxf(mi_[r], mx);
      float a = __expf(mi_[r] - mnew);
      float p0 = __expf(sv0 - mnew);
      float p1 = __expf(sv1 - mnew);
      float rs = p0 + p1;
      rs += __shfl_xor(rs, 1);
      rs += __shfl_xor(rs, 2);
      rs += __shfl_xor(rs, 4);
      rs += __shfl_xor(rs, 8);
      li_[r] = li_[r] * a + rs;
      mi_[r] = mnew;
      alph[r] = a;
      pl[(quad * 4 + r) * 32 + lanem] = f2b(p0);
      pl[(quad * 4 + r) * 32 + 16 + lanem] = f2b(p1);
    }
#pragma unroll
    for (int db = 0; db < 4; ++db) {
      floatx4 ov = o[db];
      ov[0] *= alph[0]; ov[1] *= alph[1]; ov[2] *= alph[2]; ov[3] *= alph[3];
      o[db] = ov;
    }
    // wave-private LDS round-trip: ensure writes landed before cross-lane read
    asm volatile("s_waitcnt lgkmcnt(0)" ::: "memory");
    short8 pa = *(const short8*)&pl[lanem * 32 + quad * 8];
    const u16* vb = vhT + (size_t)bh * HD_ * L_ + j0;
#pragma unroll
    for (int db = 0; db < 4; ++db) {
      short8 vf = *(const short8*)(vb + (size_t)(db * 16 + lanem) * L_ + quad * 8);
      o[db] = mfma16(pa, vf, o[db]);
    }
    asm volatile("" ::: "memory");
  }

  float inv[4];
#pragma unroll
  for (int r = 0; r < 4; ++r) inv[r] = 1.0f / li_[r];
#pragma unroll
  for (int db = 0; db < 4; ++db)
#pragma unroll
    for (int r = 0; r < 4; ++r) {
      int irow = i0 + quad * 4 + r;
      ctx[((size_t)irow * B_ + b) * E_ + h * HD_ + db * 16 + lanem] = f2b(o[db][r] * inv[r]);
    }
  if (lanem == 0) {
#pragma unroll
    for (int r = 0; r < 4; ++r) {
      int irow = i0 + quad * 4 + r;
      m_ws[(size_t)bh * L_ + irow] = mi_[r];
      li_ws[(size_t)bh * L_ + irow] = inv[r];
    }
  }
}

// ---------------- head-averaged attention probs ----------------
__global__ __launch_bounds__(256) void attn2(
    const u16* __restrict__ qh, const u16* __restrict__ kh,
    const float* __restrict__ m_ws, const float* __restrict__ li_ws,
    float* __restrict__ out2)
{
  const int jt = blockIdx.x, it = blockIdx.y, b = blockIdx.z;
  const int t = threadIdx.x, lane = t & 63, wv = t >> 6;
  const int lanem = lane & 15, quad = lane >> 4;
  const int i0 = it * 64 + wv * 16;
  const int j0 = jt * 64;

  float acc[4][4] = {};   // [s][r]
  if (j0 <= i0 + 15) {
#pragma unroll 1
    for (int h = 0; h < H_; ++h) {
      int bh = b * H_ + h;
      const u16* qb = qh + ((size_t)bh * L_ + i0 + lanem) * HD_;
      short8 qa0 = *(const short8*)(qb + quad * 8);
      short8 qa1 = *(const short8*)(qb + 32 + quad * 8);
      float mh[4], lh[4];
#pragma unroll
      for (int r = 0; r < 4; ++r) {
        mh[r] = m_ws[(size_t)bh * L_ + i0 + quad * 4 + r];
        lh[r] = li_ws[(size_t)bh * L_ + i0 + quad * 4 + r];
      }
#pragma unroll
      for (int s = 0; s < 4; ++s) {
        const u16* kb = kh + ((size_t)bh * L_ + j0 + s * 16 + lanem) * HD_;
        short8 k0f = *(const short8*)(kb + quad * 8);
        short8 k1f = *(const short8*)(kb + 32 + quad * 8);
        floatx4 sv = (floatx4){0.f, 0.f, 0.f, 0.f};
        sv = mfma16(qa0, k0f, sv);
        sv = mfma16(qa1, k1f, sv);
#pragma unroll
        for (int r = 0; r < 4; ++r) {
          int irow = i0 + quad * 4 + r;
          int jc = j0 + s * 16 + lanem;
          if (jc <= irow)
            acc[s][r] += __expf(sv[r] * 0.125f - mh[r]) * lh[r];
        }
      }
    }
  }
  float* ob = out2 + (size_t)b * L_ * L_;
#pragma unroll
  for (int s = 0; s < 4; ++s)
#pragma unroll
    for (int r = 0; r < 4; ++r) {
      int irow = i0 + quad * 4 + r;
      int jc = j0 + s * 16 + lanem;
      ob[(size_t)irow * L_ + jc] = acc[s][r] * (1.0f / H_);
    }
}

// ---------------- host ----------------
extern "C" void kernel_launch(void* const* d_in, const int* in_sizes, int n_in,
                              void* d_out, int out_size, void* d_ws, size_t ws_size,
                              hipStream_t stream) {
  const float* query = (const float*)d_in[0];
  const float* key   = (const float*)d_in[1];
  const float* value = (const float*)d_in[2];
  const float* w_in  = (const float*)d_in[3];
  const float* b_in  = (const float*)d_in[4];
  const float* w_out = (const float*)d_in[5];
  const float* b_out = (const float*)d_in[6];

  char* ws = (char*)d_ws;
  size_t off = 0;
  auto alloc = [&](size_t bytes) -> void* {
    void* p = ws + off;
    off += (bytes + 255) & ~(size_t)255;
    return p;
  };
  u16* w_in_b  = (u16*)alloc((size_t)3 * E_ * K_ * 2);
  u16* w_out_b = (u16*)alloc((size_t)E_ * K_ * 2);
  u16* x_b     = (u16*)alloc((size_t)3 * M_ * K_ * 2);
  u16* qh      = (u16*)alloc((size_t)B_ * H_ * L_ * HD_ * 2);
  u16* kh      = (u16*)alloc((size_t)B_ * H_ * L_ * HD_ * 2);
  u16* vhT     = (u16*)alloc((size_t)B_ * H_ * L_ * HD_ * 2);
  u16* ctx     = (u16*)alloc((size_t)M_ * E_ * 2);
  float* m_ws  = (float*)alloc((size_t)B_ * H_ * L_ * 4);
  float* li_ws = (float*)alloc((size_t)B_ * H_ * L_ * 4);

  // fp32 -> bf16
  convk<<<4096, 256, 0, stream>>>(query, x_b + (size_t)0 * M_ * K_, M_ * K_ / 4);
  convk<<<4096, 256, 0, stream>>>(key,   x_b + (size_t)1 * M_ * K_, M_ * K_ / 4);
  convk<<<4096, 256, 0, stream>>>(value, x_b + (size_t)2 * M_ * K_, M_ * K_ / 4);
  convk<<<3072, 256, 0, stream>>>(w_in,  w_in_b,  3 * E_ * K_ / 4);
  convk<<<1024, 256, 0, stream>>>(w_out, w_out_b, E_ * K_ / 4);

  // QKV projection (p = blockIdx.z)
  gemm128<0><<<dim3(E_ / 128, M_ / 128, 3), 256, 0, stream>>>(
      x_b, w_in_b, b_in, qh, kh, vhT, nullptr);

  // flash attention -> ctx, m, 1/l
  attn1<<<dim3(L_ / 64, H_, B_), 256, 0, stream>>>(qh, kh, vhT, ctx, m_ws, li_ws);

  // head-averaged probs -> second output
  attn2<<<dim3(L_ / 64, L_ / 64, B_), 256, 0, stream>>>(
      qh, kh, m_ws, li_ws, (float*)d_out + (size_t)M_ * E_);

  // out projection -> first output
  gemm128<1><<<dim3(E_ / 128, M_ / 128, 1), 256, 0, stream>>>(
      ctx, w_out_b, b_out, nullptr, nullptr, nullptr, (float*)d_out);
}